// Round 1
// baseline (2699.171 us; speedup 1.0000x reference)
//
#include <hip/hip_runtime.h>
#include <math.h>

// Problem constants
#define B_   16
#define C_   256
#define T_   4096
#define V_   1024
#define K_   4
#define TPB  64      // tokens per block
#define VC   128     // vectors per chunk
#define KC   128     // k (dim) per staged chunk
#define VCP  (VC+4)  // padded CBt row stride (132 floats; 528B, 16B-aligned)

constexpr int Z_ELEMS   = B_ * C_ * T_;        // 16777216
constexpr int IDX_ELEMS = B_ * K_ * T_;        // 262144
constexpr int LOSS_OFF  = Z_ELEMS + IDX_ELEMS; // 17039360

__global__ void rvq_zero_loss(float* out) { out[LOSS_OFF] = 0.0f; }

__launch_bounds__(256, 1)
__global__ void rvq_main(const float* __restrict__ z,
                         const float* __restrict__ cb,
                         float* __restrict__ out)
{
    __shared__ float Rt[C_][TPB];        // residual, transposed [c][t]  (64 KB)
    __shared__ float CBt[KC][VCP];       // codebook chunk, transposed [ck][v] (67.6 KB)
    __shared__ float Rnorm[TPB];
    __shared__ float cvpart[VC][2];      // ||c||^2 partials (two k-halves)
    __shared__ float redD[TPB][17];
    __shared__ int   redI[TPB][17];
    __shared__ int   bestIdx[TPB];
    __shared__ float rnpart[TPB][5];

    const int tid = threadIdx.x;
    const int blk = blockIdx.x;
    const int b   = blk >> 6;            // 64 blocks per batch row
    const int t0  = (blk & 63) * TPB;

    const int tx = tid & 15;             // vector group (8 v each)
    const int ty = tid >> 4;             // token group (4 t each)
    const int ut = tid & 63;             // update-phase token
    const int ug = tid >> 6;             // update-phase c-strip (64 c each)
    const int sv = tid >> 1;             // staging vector
    const int sh = tid & 1;              // staging half (64 c each)

    // ---- stage residual tile (transposed) ----
    {
        const float* zb = z + (size_t)b * C_ * T_ + t0;
        for (int j = 0; j < 64; ++j) {
            int c = ug * 64 + j;
            Rt[c][ut] = zb[(size_t)c * T_ + ut];
        }
    }
    __syncthreads();
    // ---- Rnorm init ----
    {
        float p = 0.f;
        for (int j = 0; j < 64; ++j) { float r = Rt[ug * 64 + j][ut]; p = fmaf(r, r, p); }
        rnpart[ut][ug] = p;
    }
    __syncthreads();
    if (tid < TPB)
        Rnorm[tid] = ((rnpart[tid][0] + rnpart[tid][1]) + rnpart[tid][2]) + rnpart[tid][3];
    __syncthreads();

    float loss_acc = 0.f;

    for (int st = 0; st < K_; ++st) {
        const float* cbs = cb + (size_t)st * V_ * C_;

        float bestd[4];
        int   besti[4];
        #pragma unroll
        for (int i = 0; i < 4; ++i) { bestd[i] = INFINITY; besti[i] = 0; }

        for (int vc = 0; vc < V_ / VC; ++vc) {
            float acc[4][8];
            #pragma unroll
            for (int i = 0; i < 4; ++i)
                #pragma unroll
                for (int j = 0; j < 8; ++j) acc[i][j] = 0.f;

            float cvp = 0.f;
            for (int kh = 0; kh < 2; ++kh) {
                __syncthreads();   // previous chunk/half fully consumed
                // stage CBt[ck][v] = cbs[(vc*VC+v)*C_ + kh*KC + (sh*64 + 4j+e)]
                {
                    const float* src = cbs + (size_t)(vc * VC + sv) * C_ + kh * KC + sh * 64;
                    #pragma unroll
                    for (int j4 = 0; j4 < 16; ++j4) {
                        float4 vv = *reinterpret_cast<const float4*>(src + 4 * j4);
                        int ck = sh * 64 + 4 * j4;
                        CBt[ck + 0][sv] = vv.x;
                        CBt[ck + 1][sv] = vv.y;
                        CBt[ck + 2][sv] = vv.z;
                        CBt[ck + 3][sv] = vv.w;
                        cvp = fmaf(vv.x, vv.x, cvp);
                        cvp = fmaf(vv.y, vv.y, cvp);
                        cvp = fmaf(vv.z, vv.z, cvp);
                        cvp = fmaf(vv.w, vv.w, cvp);
                    }
                }
                if (kh == 1) cvpart[sv][sh] = cvp;
                __syncthreads();

                // dot accumulation over this k-half, ascending c, separate mul/add
                const int rbase = kh * KC;
                #pragma unroll 2
                for (int ck = 0; ck < KC; ++ck) {
                    float4 r4  = *reinterpret_cast<const float4*>(&Rt[rbase + ck][4 * ty]);
                    float4 ca  = *reinterpret_cast<const float4*>(&CBt[ck][8 * tx]);
                    float4 cb4 = *reinterpret_cast<const float4*>(&CBt[ck][8 * tx + 4]);
                    float ra[4] = { r4.x, r4.y, r4.z, r4.w };
                    float cv[8] = { ca.x, ca.y, ca.z, ca.w, cb4.x, cb4.y, cb4.z, cb4.w };
                    #pragma unroll
                    for (int i = 0; i < 4; ++i)
                        #pragma unroll
                        for (int j = 0; j < 8; ++j)
                            acc[i][j] = __fadd_rn(acc[i][j], __fmul_rn(ra[i], cv[j]));
                }
            }

            // distance eval, fp32 grid semantics: d = fl(fl(R + Cv) - 2*dot)
            #pragma unroll
            for (int j = 0; j < 8; ++j) {
                int v = 8 * tx + j;
                float cv2 = __fadd_rn(cvpart[v][0], cvpart[v][1]);
                int gvi = vc * VC + v;
                #pragma unroll
                for (int i = 0; i < 4; ++i) {
                    float S = __fadd_rn(Rnorm[4 * ty + i], cv2);
                    float d = __fsub_rn(S, 2.0f * acc[i][j]);
                    if (d < bestd[i]) { bestd[i] = d; besti[i] = gvi; }  // ascending scan -> first occurrence
                }
            }
        }

        // cross-thread argmin reduce per token (lexicographic (d, idx))
        #pragma unroll
        for (int i = 0; i < 4; ++i) {
            redD[4 * ty + i][tx] = bestd[i];
            redI[4 * ty + i][tx] = besti[i];
        }
        __syncthreads();
        if (tid < TPB) {
            float bd = redD[tid][0];
            int   bi = redI[tid][0];
            for (int x = 1; x < 16; ++x) {
                float d = redD[tid][x];
                int   i2 = redI[tid][x];
                if (d < bd || (d == bd && i2 < bi)) { bd = d; bi = i2; }
            }
            bestIdx[tid] = bi;
            out[Z_ELEMS + ((size_t)b * K_ + st) * T_ + t0 + tid] = (float)bi;
        }
        __syncthreads();

        // update phase: replicate STE rounding exactly
        {
            const float* q = cbs + (size_t)bestIdx[ut] * C_ + ug * 64;
            float rn = 0.f;
            for (int j4 = 0; j4 < 16; ++j4) {
                float4 qv = *reinterpret_cast<const float4*>(q + 4 * j4);
                float qe[4] = { qv.x, qv.y, qv.z, qv.w };
                #pragma unroll
                for (int e = 0; e < 4; ++e) {
                    int c = ug * 64 + 4 * j4 + e;
                    float r   = Rt[c][ut];
                    float qmr = __fsub_rn(qe[e], r);   // sg(q - r)
                    float zq  = __fadd_rn(r, qmr);     // r + sg(q - r)
                    float lt  = __fsub_rn(zq, r);      // sg(zq) - r
                    loss_acc  = fmaf(lt, lt, loss_acc);
                    float rn2 = __fsub_rn(r, zq);      // r - sg(zq)
                    Rt[c][ut] = rn2;
                    rn = fmaf(rn2, rn2, rn);
                }
            }
            rnpart[ut][ug] = rn;
        }
        __syncthreads();
        if (tid < TPB)
            Rnorm[tid] = ((rnpart[tid][0] + rnpart[tid][1]) + rnpart[tid][2]) + rnpart[tid][3];
        __syncthreads();
    }

    // ---- epilogue: z_q = z - r_final (within ~2e-7 of ref's sum; threshold is 20.48) ----
    {
        const float* zb = z + (size_t)b * C_ * T_ + t0;
        float*       ob = out + (size_t)b * C_ * T_ + t0;
        for (int j = 0; j < 64; ++j) {
            int c = ug * 64 + j;
            ob[(size_t)c * T_ + ut] = __fsub_rn(zb[(size_t)c * T_ + ut], Rt[c][ut]);
        }
    }

    // ---- loss block-reduce -> atomicAdd ----
    __syncthreads();
    float* lred = &redD[0][0];   // 1088 floats available
    lred[tid] = loss_acc;
    __syncthreads();
    if (tid < 128) lred[tid] += lred[tid + 128];
    __syncthreads();
    if (tid < 64)  lred[tid] += lred[tid + 64];
    __syncthreads();
    if (tid == 0) {
        float s = 0.f;
        for (int i = 0; i < 64; ++i) s += lred[i];
        atomicAdd(out + LOSS_OFF, s * (1.0f / 67108864.0f));  // / (B*T*C) / K
    }
}

extern "C" void kernel_launch(void* const* d_in, const int* in_sizes, int n_in,
                              void* d_out, int out_size, void* d_ws, size_t ws_size,
                              hipStream_t stream)
{
    const float* z  = (const float*)d_in[0];
    const float* cb = (const float*)d_in[1];
    float* out = (float*)d_out;

    rvq_zero_loss<<<1, 1, 0, stream>>>(out);
    rvq_main<<<dim3(1024), dim3(256), 0, stream>>>(z, cb, out);
}

// Round 2
// 2365.836 us; speedup vs baseline: 1.1409x; 1.1409x over previous
//
#include <hip/hip_runtime.h>
#include <math.h>

// Problem constants
#define B_   16
#define C_   256
#define T_   4096
#define V_   1024
#define K_   4
#define TPB  64      // tokens per block
#define VC   256     // vectors (columns) staged per pass
#define KC   64      // k (dim) rows staged per pass
#define VCP  (VC+4)  // padded CBt row stride (260 floats = 1040B, 16B-aligned)

constexpr int Z_ELEMS   = B_ * C_ * T_;        // 16777216
constexpr int IDX_ELEMS = B_ * K_ * T_;        // 262144
constexpr int LOSS_OFF  = Z_ELEMS + IDX_ELEMS; // 17039360

__global__ void rvq_zero_loss(float* out) { out[LOSS_OFF] = 0.0f; }

__launch_bounds__(256, 1)
__global__ void rvq_main(const float* __restrict__ z,
                         const float* __restrict__ cb,
                         float* __restrict__ out)
{
    __shared__ float Rt[C_][TPB];        // residual, transposed [c][t]   (64 KB)
    __shared__ float CBt[KC][VCP];       // codebook slab [ck][v]         (66.6 KB)
    __shared__ float Rnorm[TPB];
    __shared__ float cvpart[VC][2];      // ||c||^2 partials (round-1 interleaved halves)
    __shared__ float redD[TPB][17];
    __shared__ int   redI[TPB][17];
    __shared__ int   bestIdx[TPB];
    __shared__ float rnpart[TPB][5];

    const int tid = threadIdx.x;
    const int blk = blockIdx.x;
    const int b   = blk >> 6;            // 64 blocks per batch row
    const int t0  = (blk & 63) * TPB;

    const int tx = tid & 15;             // vector group: cols {vg*64 + 4*tx + j}
    const int ty = tid >> 4;             // token group: tokens 4*ty .. 4*ty+3
    const int ut = tid & 63;             // update-phase token
    const int ug = tid >> 6;             // update-phase c-strip (64 c each)

    // ---- stage residual tile (transposed) ----
    {
        const float* zb = z + (size_t)b * C_ * T_ + t0;
        for (int j = 0; j < 64; ++j) {
            int c = ug * 64 + j;
            Rt[c][ut] = zb[(size_t)c * T_ + ut];
        }
    }
    __syncthreads();
    // ---- Rnorm init (identical chains to round 1) ----
    {
        float p = 0.f;
        for (int j = 0; j < 64; ++j) { float r = Rt[ug * 64 + j][ut]; p = fmaf(r, r, p); }
        rnpart[ut][ug] = p;
    }
    __syncthreads();
    if (tid < TPB)
        Rnorm[tid] = ((rnpart[tid][0] + rnpart[tid][1]) + rnpart[tid][2]) + rnpart[tid][3];
    __syncthreads();

    float loss_acc = 0.f;

    for (int st = 0; st < K_; ++st) {
        const float* cbs = cb + (size_t)st * V_ * C_;

        float bestd[4];
        int   besti[4];
        #pragma unroll
        for (int i = 0; i < 4; ++i) { bestd[i] = INFINITY; besti[i] = 0; }

        for (int vcg = 0; vcg < V_ / VC; ++vcg) {
            float acc[4][16];
            #pragma unroll
            for (int i = 0; i < 4; ++i)
                #pragma unroll
                for (int j = 0; j < 16; ++j) acc[i][j] = 0.f;

            // ||c||^2 partial chains — keep round-1 membership:
            // part0 = fma-chain over c in {0..63} U {128..191}  (kq 0, 2)
            // part1 = fma-chain over c in {64..127} U {192..255} (kq 1, 3)
            float cvpA = 0.f, cvpB = 0.f;

            for (int kq = 0; kq < 4; ++kq) {
                __syncthreads();   // previous slab fully consumed
                // stage CBt[ck][col] = cbs[(vcg*256+col)*C_ + kq*64 + ck], col = tid
                {
                    const float* src = cbs + (size_t)(vcg * VC + tid) * C_ + kq * KC;
                    float cvp = (kq & 1) ? cvpB : cvpA;
                    #pragma unroll
                    for (int j4 = 0; j4 < 16; ++j4) {
                        float4 vv = *reinterpret_cast<const float4*>(src + 4 * j4);
                        int ck = 4 * j4;
                        CBt[ck + 0][tid] = vv.x;
                        CBt[ck + 1][tid] = vv.y;
                        CBt[ck + 2][tid] = vv.z;
                        CBt[ck + 3][tid] = vv.w;
                        cvp = fmaf(vv.x, vv.x, cvp);
                        cvp = fmaf(vv.y, vv.y, cvp);
                        cvp = fmaf(vv.z, vv.z, cvp);
                        cvp = fmaf(vv.w, vv.w, cvp);
                    }
                    if (kq & 1) cvpB = cvp; else cvpA = cvp;
                    if (kq == 2) cvpart[tid][0] = cvpA;
                    if (kq == 3) cvpart[tid][1] = cvpB;
                }
                __syncthreads();

                // dot accumulation: ascending c, separate mul/add (bit-identical chain)
                #pragma unroll 2
                for (int ck = 0; ck < KC; ++ck) {
                    float4 r4 = *reinterpret_cast<const float4*>(&Rt[kq * KC + ck][4 * ty]);
                    float ra[4] = { r4.x, r4.y, r4.z, r4.w };
                    #pragma unroll
                    for (int vg = 0; vg < 4; ++vg) {
                        float4 cf = *reinterpret_cast<const float4*>(&CBt[ck][vg * 64 + 4 * tx]);
                        float cv[4] = { cf.x, cf.y, cf.z, cf.w };
                        #pragma unroll
                        for (int i = 0; i < 4; ++i)
                            #pragma unroll
                            for (int j = 0; j < 4; ++j)
                                acc[i][4 * vg + j] =
                                    __fadd_rn(acc[i][4 * vg + j], __fmul_rn(ra[i], cv[j]));
                    }
                }
            }

            // distance eval, fp32 grid semantics: d = fl(fl(R + Cv) - 2*dot)
            #pragma unroll
            for (int vg = 0; vg < 4; ++vg) {
                #pragma unroll
                for (int j = 0; j < 4; ++j) {
                    int col = vg * 64 + 4 * tx + j;
                    float cv2 = __fadd_rn(cvpart[col][0], cvpart[col][1]);
                    int gvi = vcg * VC + col;
                    #pragma unroll
                    for (int i = 0; i < 4; ++i) {
                        float S = __fadd_rn(Rnorm[4 * ty + i], cv2);
                        float d = __fsub_rn(S, 2.0f * acc[i][4 * vg + j]);
                        if (d < bestd[i]) { bestd[i] = d; besti[i] = gvi; }  // ascending gvi scan
                    }
                }
            }
        }

        // cross-thread argmin reduce per token (lexicographic (d, idx))
        #pragma unroll
        for (int i = 0; i < 4; ++i) {
            redD[4 * ty + i][tx] = bestd[i];
            redI[4 * ty + i][tx] = besti[i];
        }
        __syncthreads();
        if (tid < TPB) {
            float bd = redD[tid][0];
            int   bi = redI[tid][0];
            for (int x = 1; x < 16; ++x) {
                float d = redD[tid][x];
                int   i2 = redI[tid][x];
                if (d < bd || (d == bd && i2 < bi)) { bd = d; bi = i2; }
            }
            bestIdx[tid] = bi;
            out[Z_ELEMS + ((size_t)b * K_ + st) * T_ + t0 + tid] = (float)bi;
        }
        __syncthreads();

        // update phase: replicate STE rounding exactly (unchanged from round 1)
        {
            const float* q = cbs + (size_t)bestIdx[ut] * C_ + ug * 64;
            float rn = 0.f;
            for (int j4 = 0; j4 < 16; ++j4) {
                float4 qv = *reinterpret_cast<const float4*>(q + 4 * j4);
                float qe[4] = { qv.x, qv.y, qv.z, qv.w };
                #pragma unroll
                for (int e = 0; e < 4; ++e) {
                    int c = ug * 64 + 4 * j4 + e;
                    float r   = Rt[c][ut];
                    float qmr = __fsub_rn(qe[e], r);   // sg(q - r)
                    float zq  = __fadd_rn(r, qmr);     // r + sg(q - r)
                    float lt  = __fsub_rn(zq, r);      // sg(zq) - r
                    loss_acc  = fmaf(lt, lt, loss_acc);
                    float rn2 = __fsub_rn(r, zq);      // r - sg(zq)
                    Rt[c][ut] = rn2;
                    rn = fmaf(rn2, rn2, rn);
                }
            }
            rnpart[ut][ug] = rn;
        }
        __syncthreads();
        if (tid < TPB)
            Rnorm[tid] = ((rnpart[tid][0] + rnpart[tid][1]) + rnpart[tid][2]) + rnpart[tid][3];
        __syncthreads();
    }

    // ---- epilogue: z_q = z - r_final ----
    {
        const float* zb = z + (size_t)b * C_ * T_ + t0;
        float*       ob = out + (size_t)b * C_ * T_ + t0;
        for (int j = 0; j < 64; ++j) {
            int c = ug * 64 + j;
            ob[(size_t)c * T_ + ut] = __fsub_rn(zb[(size_t)c * T_ + ut], Rt[c][ut]);
        }
    }

    // ---- loss block-reduce -> atomicAdd ----
    __syncthreads();
    float* lred = &redD[0][0];
    lred[tid] = loss_acc;
    __syncthreads();
    if (tid < 128) lred[tid] += lred[tid + 128];
    __syncthreads();
    if (tid < 64)  lred[tid] += lred[tid + 64];
    __syncthreads();
    if (tid == 0) {
        float s = 0.f;
        for (int i = 0; i < 64; ++i) s += lred[i];
        atomicAdd(out + LOSS_OFF, s * (1.0f / 67108864.0f));  // / (B*T*C) / K
    }
}

extern "C" void kernel_launch(void* const* d_in, const int* in_sizes, int n_in,
                              void* d_out, int out_size, void* d_ws, size_t ws_size,
                              hipStream_t stream)
{
    const float* z  = (const float*)d_in[0];
    const float* cb = (const float*)d_in[1];
    float* out = (float*)d_out;

    rvq_zero_loss<<<1, 1, 0, stream>>>(out);
    rvq_main<<<dim3(1024), dim3(256), 0, stream>>>(z, cb, out);
}

// Round 3
// 2078.665 us; speedup vs baseline: 1.2985x; 1.1382x over previous
//
#include <hip/hip_runtime.h>
#include <math.h>

// Problem constants
#define B_   16
#define C_   256
#define T_   4096
#define V_   1024
#define K_   4
#define TPB  64      // tokens per block
#define KC   32      // k (dim) rows staged per slab
#define VCP  260     // padded CBt row stride (1040 B, 16B-aligned)

constexpr int Z_ELEMS   = B_ * C_ * T_;        // 16777216
constexpr int IDX_ELEMS = B_ * K_ * T_;        // 262144
constexpr int LOSS_OFF  = Z_ELEMS + IDX_ELEMS; // 17039360

__global__ void rvq_zero_loss(float* out) { out[LOSS_OFF] = 0.0f; }

// ||c||^2 partials, bit-identical chains to rounds 1/2:
// part0 = fma chain over c = 0..63 then 128..191
// part1 = fma chain over c = 64..127 then 192..255
__global__ void rvq_cvnorm(const float* __restrict__ cb, float2* __restrict__ cvw)
{
    int g = blockIdx.x * 256 + threadIdx.x;   // 0..4095 = st*1024 + v
    const float* row = cb + (size_t)g * C_;
    float p0 = 0.f, p1 = 0.f;
    for (int c = 0;   c < 64;  ++c) p0 = fmaf(row[c], row[c], p0);
    for (int c = 128; c < 192; ++c) p0 = fmaf(row[c], row[c], p0);
    for (int c = 64;  c < 128; ++c) p1 = fmaf(row[c], row[c], p1);
    for (int c = 192; c < 256; ++c) p1 = fmaf(row[c], row[c], p1);
    cvw[g] = make_float2(p0, p1);
}

__launch_bounds__(512, 1)
__global__ void rvq_main(const float* __restrict__ z,
                         const float* __restrict__ cb,
                         const float2* __restrict__ cvw,
                         float* __restrict__ out)
{
    __shared__ float Rt[C_][TPB];        // residual, transposed [c][t]  (64 KB)
    __shared__ float CBt[2][KC][VCP];    // per-vh codebook slab         (66.56 KB)
    __shared__ float Rnorm[TPB];
    __shared__ float redD[TPB][33];
    __shared__ int   redI[TPB][33];
    __shared__ int   bestIdx[TPB];
    __shared__ float rnpart[TPB][9];

    const int tid  = threadIdx.x;          // 0..511
    const int blk  = blockIdx.x;
    const int b    = blk >> 6;
    const int t0   = (blk & 63) * TPB;

    const int tx   = tid & 15;             // 16 cols each (4 groups of 4)
    const int ty   = (tid >> 4) & 15;      // tokens 4*ty .. 4*ty+3
    const int vh   = tid >> 8;             // V-half group
    const int gtid = tid & 255;            // column within group slab
    const int ut   = tid & 63;             // update-phase token
    const int ug   = tid >> 6;             // update-phase c-strip (8 strips x 32 c)

    // ---- stage residual tile (transposed) ----
    const float* zb = z + (size_t)b * C_ * T_ + t0;
    for (int j = 0; j < 32; ++j) {
        int c = ug * 32 + j;
        Rt[c][ut] = zb[(size_t)c * T_ + ut];
    }
    __syncthreads();
    // ---- Rnorm init (8-strip partials; argmin-safe by uniform-grid-shift) ----
    {
        float p = 0.f;
        for (int j = 0; j < 32; ++j) { float r = Rt[ug * 32 + j][ut]; p = fmaf(r, r, p); }
        rnpart[ut][ug] = p;
    }
    __syncthreads();
    if (tid < TPB) {
        float s = rnpart[tid][0];
        for (int k = 1; k < 8; ++k) s = __fadd_rn(s, rnpart[tid][k]);
        Rnorm[tid] = s;
    }
    __syncthreads();

    float loss_acc = 0.f;

    for (int st = 0; st < K_; ++st) {
        const float* cbs = cb + (size_t)st * V_ * C_;

        float bestd[4];
        int   besti[4];
        #pragma unroll
        for (int i = 0; i < 4; ++i) { bestd[i] = INFINITY; besti[i] = 0; }

        for (int vcg = 0; vcg < 2; ++vcg) {
            const int colbase = vcg * 512 + vh * 256;

            float acc[4][16];
            #pragma unroll
            for (int i = 0; i < 4; ++i)
                #pragma unroll
                for (int j = 0; j < 16; ++j) acc[i][j] = 0.f;

            for (int slab = 0; slab < 8; ++slab) {
                __syncthreads();   // previous slab fully consumed / Rt update done
                // stage CBt[vh][ck][gtid] = cbs[(colbase+gtid)*C_ + slab*32 + ck]
                {
                    const float* src = cbs + (size_t)(colbase + gtid) * C_ + slab * KC;
                    #pragma unroll
                    for (int j4 = 0; j4 < 8; ++j4) {
                        float4 vv = *reinterpret_cast<const float4*>(src + 4 * j4);
                        int ck = 4 * j4;
                        CBt[vh][ck + 0][gtid] = vv.x;
                        CBt[vh][ck + 1][gtid] = vv.y;
                        CBt[vh][ck + 2][gtid] = vv.z;
                        CBt[vh][ck + 3][gtid] = vv.w;
                    }
                }
                __syncthreads();

                // dot accumulation: ascending c, separate mul/add (bit-identical chain)
                #pragma unroll 2
                for (int ck = 0; ck < KC; ++ck) {
                    float4 r4 = *reinterpret_cast<const float4*>(&Rt[slab * KC + ck][4 * ty]);
                    float ra[4] = { r4.x, r4.y, r4.z, r4.w };
                    #pragma unroll
                    for (int vg = 0; vg < 4; ++vg) {
                        float4 cf = *reinterpret_cast<const float4*>(&CBt[vh][ck][vg * 64 + 4 * tx]);
                        float cv[4] = { cf.x, cf.y, cf.z, cf.w };
                        #pragma unroll
                        for (int i = 0; i < 4; ++i)
                            #pragma unroll
                            for (int j = 0; j < 4; ++j)
                                acc[i][4 * vg + j] =
                                    __fadd_rn(acc[i][4 * vg + j], __fmul_rn(ra[i], cv[j]));
                    }
                }
            }

            // distance eval: d = fl(fl(Rnorm + cv2) - 2*dot), ascending gvi scan
            #pragma unroll
            for (int vg = 0; vg < 4; ++vg) {
                #pragma unroll
                for (int j = 0; j < 4; ++j) {
                    int col = vg * 64 + 4 * tx + j;
                    int gvi = colbase + col;
                    float2 pv = cvw[st * V_ + gvi];
                    float cv2 = __fadd_rn(pv.x, pv.y);
                    #pragma unroll
                    for (int i = 0; i < 4; ++i) {
                        float S = __fadd_rn(Rnorm[4 * ty + i], cv2);
                        float d = __fsub_rn(S, 2.0f * acc[i][4 * vg + j]);
                        if (d < bestd[i]) { bestd[i] = d; besti[i] = gvi; }
                    }
                }
            }
        }

        // cross-thread argmin reduce per token (lexicographic (d, idx))
        #pragma unroll
        for (int i = 0; i < 4; ++i) {
            redD[4 * ty + i][vh * 16 + tx] = bestd[i];
            redI[4 * ty + i][vh * 16 + tx] = besti[i];
        }
        __syncthreads();
        if (tid < TPB) {
            float bd = redD[tid][0];
            int   bi = redI[tid][0];
            for (int x = 1; x < 32; ++x) {
                float d  = redD[tid][x];
                int   i2 = redI[tid][x];
                if (d < bd || (d == bd && i2 < bi)) { bd = d; bi = i2; }
            }
            bestIdx[tid] = bi;
            out[Z_ELEMS + ((size_t)b * K_ + st) * T_ + t0 + tid] = (float)bi;
        }
        __syncthreads();

        // update phase: replicate STE rounding exactly (per-element chains unchanged)
        {
            const float* q = cbs + (size_t)bestIdx[ut] * C_ + ug * 32;
            float rn = 0.f;
            for (int j4 = 0; j4 < 8; ++j4) {
                float4 qv = *reinterpret_cast<const float4*>(q + 4 * j4);
                float qe[4] = { qv.x, qv.y, qv.z, qv.w };
                #pragma unroll
                for (int e = 0; e < 4; ++e) {
                    int c = ug * 32 + 4 * j4 + e;
                    float r   = Rt[c][ut];
                    float qmr = __fsub_rn(qe[e], r);   // sg(q - r)
                    float zq  = __fadd_rn(r, qmr);     // r + sg(q - r)
                    float lt  = __fsub_rn(zq, r);      // sg(zq) - r
                    loss_acc  = fmaf(lt, lt, loss_acc);
                    float rn2 = __fsub_rn(r, zq);      // r - sg(zq)
                    Rt[c][ut] = rn2;
                    rn = fmaf(rn2, rn2, rn);
                }
            }
            rnpart[ut][ug] = rn;
        }
        __syncthreads();
        if (tid < TPB) {
            float s = rnpart[tid][0];
            for (int k = 1; k < 8; ++k) s = __fadd_rn(s, rnpart[tid][k]);
            Rnorm[tid] = s;
        }
        __syncthreads();
    }

    // ---- epilogue: z_q = z - r_final ----
    {
        float* ob = out + (size_t)b * C_ * T_ + t0;
        for (int j = 0; j < 32; ++j) {
            int c = ug * 32 + j;
            ob[(size_t)c * T_ + ut] = __fsub_rn(zb[(size_t)c * T_ + ut], Rt[c][ut]);
        }
    }

    // ---- loss block-reduce -> atomicAdd ----
    __syncthreads();
    float* lred = &redD[0][0];   // 2112 floats available
    lred[tid] = loss_acc;
    __syncthreads();
    if (tid < 256) lred[tid] += lred[tid + 256];
    __syncthreads();
    if (tid < 128) lred[tid] += lred[tid + 128];
    __syncthreads();
    if (tid < 64)  lred[tid] += lred[tid + 64];
    __syncthreads();
    if (tid == 0) {
        float s = 0.f;
        for (int i = 0; i < 64; ++i) s += lred[i];
        atomicAdd(out + LOSS_OFF, s * (1.0f / 67108864.0f));  // / (B*T*C) / K
    }
}

extern "C" void kernel_launch(void* const* d_in, const int* in_sizes, int n_in,
                              void* d_out, int out_size, void* d_ws, size_t ws_size,
                              hipStream_t stream)
{
    const float* z  = (const float*)d_in[0];
    const float* cb = (const float*)d_in[1];
    float* out = (float*)d_out;
    float2* cvw = (float2*)d_ws;         // 4*1024 float2 = 32 KB scratch

    rvq_zero_loss<<<1, 1, 0, stream>>>(out);
    rvq_cvnorm<<<16, 256, 0, stream>>>(cb, cvw);
    rvq_main<<<dim3(1024), dim3(512), 0, stream>>>(z, cb, cvw, out);
}

// Round 4
// 800.808 us; speedup vs baseline: 3.3706x; 2.5957x over previous
//
#include <hip/hip_runtime.h>
#include <math.h>

// Problem constants
#define B_   16
#define C_   256
#define T_   4096
#define V_   1024
#define K_   4
#define TPB  64      // tokens per block
#define EPS_CAND 2e-4f

constexpr int Z_ELEMS   = B_ * C_ * T_;        // 16777216
constexpr int IDX_ELEMS = B_ * K_ * T_;        // 262144
constexpr int LOSS_OFF  = Z_ELEMS + IDX_ELEMS; // 17039360

typedef _Float16 h4 __attribute__((ext_vector_type(4)));
typedef float    f4 __attribute__((ext_vector_type(4)));

__global__ void rvq_zero_loss(float* out) { out[LOSS_OFF] = 0.0f; }

// ||c||^2 partials, bit-identical chains to rounds 1-3:
// part0 = fma chain over c = 0..63 then 128..191
// part1 = fma chain over c = 64..127 then 192..255
__global__ void rvq_cvnorm(const float* __restrict__ cb, float2* __restrict__ cvw)
{
    int g = blockIdx.x * 256 + threadIdx.x;   // 0..4095 = st*1024 + v
    const float* row = cb + (size_t)g * C_;
    float p0 = 0.f, p1 = 0.f;
    for (int c = 0;   c < 64;  ++c) p0 = fmaf(row[c], row[c], p0);
    for (int c = 128; c < 192; ++c) p0 = fmaf(row[c], row[c], p0);
    for (int c = 64;  c < 128; ++c) p1 = fmaf(row[c], row[c], p1);
    for (int c = 192; c < 256; ++c) p1 = fmaf(row[c], row[c], p1);
    cvw[g] = make_float2(p0, p1);
}

// Codebook -> f16 B-fragments (scaled by 16 to dodge f16 subnormals).
// Fragment layout for mfma_f32_16x16x16f16:
//   elem i of lane l in tile nt, k-step ks = B[k=ks*16+4*(l>>4)+i][n=nt*16+(l&15)]
// Stored flat: cbh4[((st*64+nt)*16 + ks)*64 + l]
__global__ void rvq_cbf16(const float* __restrict__ cb, _Float16* __restrict__ cbh)
{
    int gid = blockIdx.x * 256 + threadIdx.x;   // 262144 quads
    int l  = gid & 63;
    int ks = (gid >> 6) & 15;
    int nt = (gid >> 10) & 63;
    int st = gid >> 16;
    int v  = nt * 16 + (l & 15);
    int k  = ks * 16 + 4 * (l >> 4);
    const float* src = cb + ((size_t)(st * V_ + v)) * C_ + k;
    float4 cv = *reinterpret_cast<const float4*>(src);
    h4 o;
    o[0] = (_Float16)(cv.x * 16.0f);
    o[1] = (_Float16)(cv.y * 16.0f);
    o[2] = (_Float16)(cv.z * 16.0f);
    o[3] = (_Float16)(cv.w * 16.0f);
    reinterpret_cast<h4*>(cbh)[gid] = o;
}

__launch_bounds__(512, 2)
__global__ void rvq_main(const float* __restrict__ z,
                         const float* __restrict__ cb,
                         const float2* __restrict__ cvw,
                         const _Float16* __restrict__ cbh,
                         float* __restrict__ out)
{
    __shared__ float Rt[C_][TPB];          // residual, transposed [c][t] (64 KB)
    __shared__ _Float16 Ah[TPB * C_];      // f16 A-operand, [m][k] XOR-swizzled (32 KB)
    __shared__ float gmin[8][TPB];         // per-wave token mins (2 KB); reused for loss
    __shared__ float fmin[TPB];
    __shared__ int   candCnt[TPB];
    __shared__ int   candIdx[TPB][8];
    __shared__ float pbD[TPB][8];
    __shared__ int   pbI[TPB][8];
    __shared__ int   bestIdx[TPB];
    __shared__ float rnpart[TPB][9];
    __shared__ float Rnorm[TPB];

    const int tid = threadIdx.x;           // 0..511
    const int blk = blockIdx.x;
    const int b   = blk >> 6;
    const int t0  = (blk & 63) * TPB;

    const int w   = tid >> 6;              // wave id: n-stripe of 128 vectors
    const int l   = tid & 63;              // lane
    const int ut  = tid & 63;              // update-phase token
    const int ug  = tid >> 6;              // update-phase c-strip (8 x 32)

    char* AhB = reinterpret_cast<char*>(Ah);

    // ---- stage residual tile (transposed) ----
    const float* zb = z + (size_t)b * C_ * T_ + t0;
    for (int j = 0; j < 32; ++j) {
        int c = ug * 32 + j;
        Rt[c][ut] = zb[(size_t)c * T_ + ut];
    }
    __syncthreads();
    // ---- Rnorm init (identical chains to round 3) ----
    {
        float p = 0.f;
        for (int j = 0; j < 32; ++j) { float r = Rt[ug * 32 + j][ut]; p = fmaf(r, r, p); }
        rnpart[ut][ug] = p;
    }
    __syncthreads();
    if (tid < TPB) {
        float s = rnpart[tid][0];
        for (int k = 1; k < 8; ++k) s = __fadd_rn(s, rnpart[tid][k]);
        Rnorm[tid] = s;
    }
    __syncthreads();

    float loss_acc = 0.f;

    for (int st = 0; st < K_; ++st) {
        const float* cbs = cb + (size_t)st * V_ * C_;

        // ---- build f16 A-operand from Rt: Ah[m][k] swizzled ----
        {
            int m  = tid & 63;
            int k0 = (tid >> 6) * 32;
            #pragma unroll
            for (int j4 = 0; j4 < 8; ++j4) {
                int k = k0 + 4 * j4;
                h4 hv;
                hv[0] = (_Float16)Rt[k + 0][m];
                hv[1] = (_Float16)Rt[k + 1][m];
                hv[2] = (_Float16)Rt[k + 2][m];
                hv[3] = (_Float16)Rt[k + 3][m];
                int off = (m * 512 + k * 2) ^ ((m & 7) << 4);
                *reinterpret_cast<h4*>(AhB + off) = hv;
            }
        }
        __syncthreads();

        // ---- Phase A: f16 GEMM, acc[mt][nf] = 16 * (r . c) fragments ----
        f4 acc[4][8];
        #pragma unroll
        for (int mt = 0; mt < 4; ++mt)
            #pragma unroll
            for (int nf = 0; nf < 8; ++nf)
                acc[mt][nf] = (f4){0.f, 0.f, 0.f, 0.f};

        {
            const h4* cbh4 = reinterpret_cast<const h4*>(cbh);
            const size_t wbase = (size_t)st * 65536 + (size_t)(w * 8) * 1024 + l;
            #pragma unroll 4
            for (int ks = 0; ks < 16; ++ks) {
                h4 af[4];
                #pragma unroll
                for (int mt = 0; mt < 4; ++mt) {
                    int mG = mt * 16 + (l & 15);
                    int off = (mG * 512 + ks * 32 + (l >> 4) * 8) ^ ((mG & 7) << 4);
                    af[mt] = *reinterpret_cast<const h4*>(AhB + off);
                }
                #pragma unroll
                for (int nf = 0; nf < 8; ++nf) {
                    h4 bf = cbh4[wbase + (size_t)nf * 1024 + ks * 64];
                    #pragma unroll
                    for (int mt = 0; mt < 4; ++mt)
                        acc[mt][nf] = __builtin_amdgcn_mfma_f32_16x16x16f16(af[mt], bf, acc[mt][nf], 0, 0, 0);
                }
            }
        }

        // ---- convert acc -> approx distances d' = cv2 - 0.125*acc ----
        float cv2v[8];
        #pragma unroll
        for (int nf = 0; nf < 8; ++nf) {
            int v = w * 128 + nf * 16 + (l & 15);
            float2 pv = cvw[st * V_ + v];
            cv2v[nf] = __fadd_rn(pv.x, pv.y);
        }
        #pragma unroll
        for (int mt = 0; mt < 4; ++mt)
            #pragma unroll
            for (int nf = 0; nf < 8; ++nf)
                #pragma unroll
                for (int jj = 0; jj < 4; ++jj)
                    acc[mt][nf][jj] = fmaf(acc[mt][nf][jj], -0.125f, cv2v[nf]);

        // ---- per-token min: lane-local over nf, then across 16 lanes ----
        float tmin[4][4];
        #pragma unroll
        for (int mt = 0; mt < 4; ++mt)
            #pragma unroll
            for (int jj = 0; jj < 4; ++jj) {
                float m0 = acc[mt][0][jj];
                #pragma unroll
                for (int nf = 1; nf < 8; ++nf) m0 = fminf(m0, acc[mt][nf][jj]);
                tmin[mt][jj] = m0;
            }
        #pragma unroll
        for (int mt = 0; mt < 4; ++mt)
            #pragma unroll
            for (int jj = 0; jj < 4; ++jj) {
                float m0 = tmin[mt][jj];
                m0 = fminf(m0, __shfl_xor(m0, 1, 16));
                m0 = fminf(m0, __shfl_xor(m0, 2, 16));
                m0 = fminf(m0, __shfl_xor(m0, 4, 16));
                m0 = fminf(m0, __shfl_xor(m0, 8, 16));
                tmin[mt][jj] = m0;
            }
        if ((l & 15) == 0) {
            #pragma unroll
            for (int mt = 0; mt < 4; ++mt)
                #pragma unroll
                for (int jj = 0; jj < 4; ++jj)
                    gmin[w][mt * 16 + 4 * (l >> 4) + jj] = tmin[mt][jj];
        }
        __syncthreads();
        if (tid < TPB) {
            float mm = gmin[0][tid];
            #pragma unroll
            for (int ww = 1; ww < 8; ++ww) mm = fminf(mm, gmin[ww][tid]);
            fmin[tid] = mm;
            candCnt[tid] = 0;
        }
        __syncthreads();

        // ---- candidate scan & push ----
        {
            float fthr[4][4];
            #pragma unroll
            for (int mt = 0; mt < 4; ++mt)
                #pragma unroll
                for (int jj = 0; jj < 4; ++jj)
                    fthr[mt][jj] = fmin[mt * 16 + 4 * (l >> 4) + jj] + EPS_CAND;
            #pragma unroll
            for (int mt = 0; mt < 4; ++mt)
                #pragma unroll
                for (int nf = 0; nf < 8; ++nf)
                    #pragma unroll
                    for (int jj = 0; jj < 4; ++jj)
                        if (acc[mt][nf][jj] <= fthr[mt][jj]) {
                            int tok = mt * 16 + 4 * (l >> 4) + jj;
                            int s = atomicAdd(&candCnt[tok], 1);
                            if (s < 8) candIdx[tok][s] = w * 128 + nf * 16 + (l & 15);
                        }
        }
        __syncthreads();

        // ---- Phase B: exact fp32-chain distance for candidates ----
        {
            int t = tid & 63, s = tid >> 6;
            int nc = candCnt[t]; if (nc > 8) nc = 8;
            if (s < nc) {
                int gi = candIdx[t][s];
                const float* crow = cbs + (size_t)gi * C_;
                float dot = 0.f;
                for (int c = 0; c < 256; c += 4) {
                    float4 cr = *reinterpret_cast<const float4*>(crow + c);
                    dot = __fadd_rn(dot, __fmul_rn(Rt[c + 0][t], cr.x));
                    dot = __fadd_rn(dot, __fmul_rn(Rt[c + 1][t], cr.y));
                    dot = __fadd_rn(dot, __fmul_rn(Rt[c + 2][t], cr.z));
                    dot = __fadd_rn(dot, __fmul_rn(Rt[c + 3][t], cr.w));
                }
                float2 pv = cvw[st * V_ + gi];
                float cv2 = __fadd_rn(pv.x, pv.y);
                float S = __fadd_rn(Rnorm[t], cv2);
                pbD[t][s] = __fsub_rn(S, 2.0f * dot);
                pbI[t][s] = gi;
            }
        }
        __syncthreads();
        if (tid < TPB) {
            int nc = candCnt[tid]; if (nc > 8) nc = 8;
            float bd = pbD[tid][0];
            int   bi = pbI[tid][0];
            for (int s = 1; s < nc; ++s) {
                float d  = pbD[tid][s];
                int   i2 = pbI[tid][s];
                if (d < bd || (d == bd && i2 < bi)) { bd = d; bi = i2; }
            }
            bestIdx[tid] = bi;
            out[Z_ELEMS + ((size_t)b * K_ + st) * T_ + t0 + tid] = (float)bi;
        }
        __syncthreads();

        // ---- update phase: replicate STE rounding exactly (unchanged) ----
        {
            const float* q = cbs + (size_t)bestIdx[ut] * C_ + ug * 32;
            float rn = 0.f;
            for (int j4 = 0; j4 < 8; ++j4) {
                float4 qv = *reinterpret_cast<const float4*>(q + 4 * j4);
                float qe[4] = { qv.x, qv.y, qv.z, qv.w };
                #pragma unroll
                for (int e = 0; e < 4; ++e) {
                    int c = ug * 32 + 4 * j4 + e;
                    float r   = Rt[c][ut];
                    float qmr = __fsub_rn(qe[e], r);   // sg(q - r)
                    float zq  = __fadd_rn(r, qmr);     // r + sg(q - r)
                    float lt  = __fsub_rn(zq, r);      // sg(zq) - r
                    loss_acc  = fmaf(lt, lt, loss_acc);
                    float rn2 = __fsub_rn(r, zq);      // r - sg(zq)
                    Rt[c][ut] = rn2;
                    rn = fmaf(rn2, rn2, rn);
                }
            }
            rnpart[ut][ug] = rn;
        }
        __syncthreads();
        if (tid < TPB) {
            float s = rnpart[tid][0];
            for (int k = 1; k < 8; ++k) s = __fadd_rn(s, rnpart[tid][k]);
            Rnorm[tid] = s;
        }
        __syncthreads();
    }

    // ---- epilogue: z_q = z - r_final ----
    {
        float* ob = out + (size_t)b * C_ * T_ + t0;
        for (int j = 0; j < 32; ++j) {
            int c = ug * 32 + j;
            ob[(size_t)c * T_ + ut] = __fsub_rn(zb[(size_t)c * T_ + ut], Rt[c][ut]);
        }
    }

    // ---- loss block-reduce -> atomicAdd (reuse gmin as scratch) ----
    __syncthreads();
    float* lred = &gmin[0][0];   // 512 floats
    lred[tid] = loss_acc;
    __syncthreads();
    if (tid < 256) lred[tid] += lred[tid + 256];
    __syncthreads();
    if (tid < 128) lred[tid] += lred[tid + 128];
    __syncthreads();
    if (tid < 64)  lred[tid] += lred[tid + 64];
    __syncthreads();
    if (tid == 0) {
        float s = 0.f;
        for (int i = 0; i < 64; ++i) s += lred[i];
        atomicAdd(out + LOSS_OFF, s * (1.0f / 67108864.0f));  // / (B*T*C) / K
    }
}

extern "C" void kernel_launch(void* const* d_in, const int* in_sizes, int n_in,
                              void* d_out, int out_size, void* d_ws, size_t ws_size,
                              hipStream_t stream)
{
    const float* z  = (const float*)d_in[0];
    const float* cb = (const float*)d_in[1];
    float* out = (float*)d_out;
    float2*    cvw = (float2*)d_ws;                              // 32 KB
    _Float16*  cbh = (_Float16*)((char*)d_ws + 32768);           // 2 MB

    rvq_zero_loss<<<1, 1, 0, stream>>>(out);
    rvq_cvnorm<<<16, 256, 0, stream>>>(cb, cvw);
    rvq_cbf16<<<1024, 256, 0, stream>>>(cb, cbh);
    rvq_main<<<dim3(1024), dim3(512), 0, stream>>>(z, cb, cvw, cbh, out);
}